// Round 11
// baseline (131.371 us; speedup 1.0000x reference)
//
#include <hip/hip_runtime.h>
#include <stdint.h>

typedef __attribute__((ext_vector_type(8))) __bf16 bf16x8;
typedef __attribute__((ext_vector_type(16))) float f32x16;
typedef __attribute__((ext_vector_type(4))) unsigned int u32x4;
typedef __attribute__((ext_vector_type(2))) float f32x2;
typedef unsigned int u32;
typedef unsigned short u16;

#define THETA 0.7f

__host__ __device__ constexpr float pht_val(int q) {
  return (q == 12) ? (-4.0f + 1e-6f)
       : (q == 7 || q == 11 || q == 13 || q == 17) ? (1.0f + 1e-6f)
       : 1e-6f;
}

__device__ __forceinline__ u16 f2bf(float v) {
  u32 u = __builtin_bit_cast(u32, v);
  return (u16)((u + 0x7fffu + ((u >> 16) & 1u)) >> 16);
}

// ---------------- kernel 1: build K_eff, packed as MFMA A-fragments -------
__global__ __launch_bounds__(256) void k_prep(const float* __restrict__ wgt,
                                              const float* __restrict__ alpha,
                                              u16* __restrict__ apack) {
  int t = blockIdx.x * 256 + threadIdx.x;   // 4096 threads: (o, ci)
  int o = t >> 6, ci = t & 63;
  const float* wp = wgt + ((size_t)(o * 64 + ci)) * 25;
  float wv[25], sumw = 0.f;
#pragma unroll
  for (int p = 0; p < 25; ++p) { wv[p] = wp[p]; sumw += wv[p]; }
  float keff[25];
#pragma unroll
  for (int p = 0; p < 25; ++p) keff[p] = pht_val(p) * wv[p];  // a=0 (identity)
  constexpr int TP[33] = {0,1,2,3,4,6,7,9,12,13,  0,1,2,3,4,  0, 0, 0,
                          0,5,10,15,20,  0,5,6,10,11,12,15,17,20,21};
  constexpr int TQ[33] = {5,6,12,17,23,10,16,22,20,21,  0,5,10,15,20,  5, 0, 5,
                          0,6,7,8,9,  5,6,2,12,8,4,17,9,23,14};
#pragma unroll
  for (int e = 0; e < 33; ++e) keff[TP[e]] += pht_val(TQ[e]) * wv[TQ[e]];

  float al = alpha[0];
  int kc = ci >> 4, oh = o >> 5;
  int lane = ((ci >> 3) & 1) * 32 + (o & 31);   // A-frag: lane=(k/8)*32+m
#pragma unroll
  for (int p = 0; p < 25; ++p) {
    float v = al * (keff[p] * 0.125f);
    if (p == 12) v -= THETA * sumw;             // fold 1x1 branch into center
    size_t idx = ((((size_t)p * 4 + kc) * 2 + oh) * 64 + lane) * 8 + (ci & 7);
    apack[idx] = f2bf(v);
  }
}

// ---------------- kernel 2: FUSED conv (cast+stage+MFMA) ------------------
// 32-px tile: 8 rows x 36 cols x 128 B = 36 KB LDS -> 4 blocks/CU (desync).
// 128 thr = 2 waves (oh halves); each wave: 4 rows x 32 px x 32 o.
// Stage: thread = (col-pair, granule): 8 coalesced f32x2 loads -> f2bf pack
// -> 2 ds_write_b128 (bank-balanced: phys granule g^(c&7) covers all 8).
// Compute/epilogue: R9/R10 verbatim (SGB-pipelined 20-iter, 400 MFMA/wave).
#define ROWB 4608   // 36 cols * 128 B

#define MM(A, B, C) __builtin_amdgcn_mfma_f32_32x32x16_bf16((A), __builtin_bit_cast(bf16x8, (B)), (C), 0, 0, 0)

#define LDBR(S, DX, KC) do {                                                \
    const char* pb_ = pcol + (DX) * 128;                                    \
    int gx_ = ((((KC) * 2 + lhi) ^ ((l31 + (DX)) & 7)) << 4);               \
    br##S##0 = *(const u32x4*)(pb_ + 0 * ROWB + gx_);                       \
    br##S##1 = *(const u32x4*)(pb_ + 1 * ROWB + gx_);                       \
    br##S##2 = *(const u32x4*)(pb_ + 2 * ROWB + gx_);                       \
    br##S##3 = *(const u32x4*)(pb_ + 3 * ROWB + gx_);                       \
    br##S##4 = *(const u32x4*)(pb_ + 4 * ROWB + gx_);                       \
    br##S##5 = *(const u32x4*)(pb_ + 5 * ROWB + gx_);                       \
    br##S##6 = *(const u32x4*)(pb_ + 6 * ROWB + gx_);                       \
    br##S##7 = *(const u32x4*)(pb_ + 7 * ROWB + gx_);                       \
  } while (0)

#define LDAF(S, DX, KC) do {                                                \
    af##S##0 = apb[(size_t)((0 * 5 + (DX)) * 512 + (KC) * 128)];            \
    af##S##1 = apb[(size_t)((1 * 5 + (DX)) * 512 + (KC) * 128)];            \
    af##S##2 = apb[(size_t)((2 * 5 + (DX)) * 512 + (KC) * 128)];            \
    af##S##3 = apb[(size_t)((3 * 5 + (DX)) * 512 + (KC) * 128)];            \
    af##S##4 = apb[(size_t)((4 * 5 + (DX)) * 512 + (KC) * 128)];            \
  } while (0)

#define BURST(S) do {                                                       \
    bf16x8 A_;                                                              \
    A_ = __builtin_bit_cast(bf16x8, af##S##0);                              \
    a0 = MM(A_, br##S##0, a0); a1 = MM(A_, br##S##1, a1);                   \
    a2 = MM(A_, br##S##2, a2); a3 = MM(A_, br##S##3, a3);                   \
    A_ = __builtin_bit_cast(bf16x8, af##S##1);                              \
    a0 = MM(A_, br##S##1, a0); a1 = MM(A_, br##S##2, a1);                   \
    a2 = MM(A_, br##S##3, a2); a3 = MM(A_, br##S##4, a3);                   \
    A_ = __builtin_bit_cast(bf16x8, af##S##2);                              \
    a0 = MM(A_, br##S##2, a0); a1 = MM(A_, br##S##3, a1);                   \
    a2 = MM(A_, br##S##4, a2); a3 = MM(A_, br##S##5, a3);                   \
    A_ = __builtin_bit_cast(bf16x8, af##S##3);                              \
    a0 = MM(A_, br##S##3, a0); a1 = MM(A_, br##S##4, a1);                   \
    a2 = MM(A_, br##S##5, a2); a3 = MM(A_, br##S##6, a3);                   \
    A_ = __builtin_bit_cast(bf16x8, af##S##4);                              \
    a0 = MM(A_, br##S##4, a0); a1 = MM(A_, br##S##5, a1);                   \
    a2 = MM(A_, br##S##6, a2); a3 = MM(A_, br##S##7, a3);                   \
  } while (0)

#define SGB __builtin_amdgcn_sched_group_barrier
#define SCHED_FULL() do {                                                   \
    SGB(0x020, 5, 0);              /* 5 VMEM (next af) early */             \
    SGB(0x100, 2, 0); SGB(0x008, 5, 0);                                     \
    SGB(0x100, 2, 0); SGB(0x008, 5, 0);                                     \
    SGB(0x100, 2, 0); SGB(0x008, 5, 0);                                     \
    SGB(0x100, 2, 0); SGB(0x008, 5, 0);                                     \
  } while (0)

#define ITER(CUR, NXT, DXN, KCN) do {                                       \
    LDBR(NXT, DXN, KCN); LDAF(NXT, DXN, KCN); BURST(CUR); SCHED_FULL();     \
  } while (0)

// stage one (col-pair CP, granule GG) slot of the current row
#define STAGE_SLOT(CP, GG) do {                                             \
    int pxb_ = px0 + 2 * (CP) - 2;                                          \
    bool ok_ = rowok && ((unsigned)pxb_ < 128u);                            \
    const float* ps_ = xr + (size_t)(8 * (GG)) * 16384 + pxb_;              \
    f32x2 v0 = {0.f, 0.f}, v1 = {0.f, 0.f}, v2 = {0.f, 0.f}, v3 = {0.f, 0.f}; \
    f32x2 v4 = {0.f, 0.f}, v5 = {0.f, 0.f}, v6 = {0.f, 0.f}, v7 = {0.f, 0.f}; \
    if (ok_) {                                                              \
      v0 = *(const f32x2*)(ps_);                                            \
      v1 = *(const f32x2*)(ps_ + 16384);                                    \
      v2 = *(const f32x2*)(ps_ + 2 * 16384);                                \
      v3 = *(const f32x2*)(ps_ + 3 * 16384);                                \
      v4 = *(const f32x2*)(ps_ + 4 * 16384);                                \
      v5 = *(const f32x2*)(ps_ + 5 * 16384);                                \
      v6 = *(const f32x2*)(ps_ + 6 * 16384);                                \
      v7 = *(const f32x2*)(ps_ + 7 * 16384);                                \
    }                                                                       \
    u32x4 wx_, wy_;                                                         \
    wx_[0] = (u32)f2bf(v0.x) | ((u32)f2bf(v1.x) << 16);                     \
    wx_[1] = (u32)f2bf(v2.x) | ((u32)f2bf(v3.x) << 16);                     \
    wx_[2] = (u32)f2bf(v4.x) | ((u32)f2bf(v5.x) << 16);                     \
    wx_[3] = (u32)f2bf(v6.x) | ((u32)f2bf(v7.x) << 16);                     \
    wy_[0] = (u32)f2bf(v0.y) | ((u32)f2bf(v1.y) << 16);                     \
    wy_[1] = (u32)f2bf(v2.y) | ((u32)f2bf(v3.y) << 16);                     \
    wy_[2] = (u32)f2bf(v4.y) | ((u32)f2bf(v5.y) << 16);                     \
    wy_[3] = (u32)f2bf(v6.y) | ((u32)f2bf(v7.y) << 16);                     \
    int c0_ = 2 * (CP);                                                     \
    *(u32x4*)(rowbase + c0_ * 128 + (((GG) ^ (c0_ & 7)) << 4)) = wx_;       \
    *(u32x4*)(rowbase + (c0_ + 1) * 128 + (((GG) ^ ((c0_ + 1) & 7)) << 4)) = wy_; \
  } while (0)

__global__ __launch_bounds__(128, 2) void k_conv(const float* __restrict__ x,
                                                 const u32x4* __restrict__ apv,
                                                 float* __restrict__ out) {
  __shared__ char tile[8 * ROWB];             // 36864 B -> 4 blocks/CU
  int bid = blockIdx.x;
  int lg = (bid & 7) * 512 + (bid >> 3);      // XCD swizzle (4096%8==0)
  int pxq = lg & 3, yt = (lg >> 2) & 31, n = lg >> 7;
  int y0 = yt * 4, px0 = pxq * 32;
  int tid = threadIdx.x;
  int l = tid & 63;

  // ---- fused stage: x fp32 -> bf16 -> swizzled tile[r][c][i] ----
  // col c holds src px = px0 + c - 2; ch i at pre-swizzle byte i*2,
  // granule (i>>3) XOR (c&7).
  {
    const float* xn = x + (size_t)n * (64 * 16384);
    int sp = tid & 15, sg = tid >> 4;         // main slot: 16 cp x 8 g = 128
    int hp = 16 + (tid >> 3), hg = tid & 7;   // halo slot (threads 0..15)
#pragma unroll
    for (int rr = 0; rr < 8; ++rr) {
      int sy = y0 + rr - 2;
      bool rowok = (unsigned)sy < 128u;
      char* rowbase = tile + rr * ROWB;
      const float* xr = xn + (size_t)sy * 128;
      STAGE_SLOT(sp, sg);                     // cols 0..31
      if (tid < 16) STAGE_SLOT(hp, hg);       // cols 32..35
    }
  }

  // ---- compute: wave = oh (o-half); all 4 rows x 32 px x 32 o ----
  int oh = tid >> 6;
  int l31 = l & 31, lhi = l >> 5;
  const u32x4* apb = apv + (size_t)(oh * 64 + l);
  const char* pcol = tile + l31 * 128;

  u32x4 brA0, brA1, brA2, brA3, brA4, brA5, brA6, brA7;
  u32x4 brB0, brB1, brB2, brB3, brB4, brB5, brB6, brB7;
  u32x4 afA0, afA1, afA2, afA3, afA4;
  u32x4 afB0, afB1, afB2, afB3, afB4;

  LDAF(A, 0, 0);                              // iter-0 A-frags hide under
  __syncthreads();                            // the stage drain
  LDBR(A, 0, 0);

  f32x16 a0 = 0, a1 = 0, a2 = 0, a3 = 0;      // acc[row]

  // 20 iterations, (dx outer, kc inner), alternating register sets
  ITER(A, B, 0, 1);
  ITER(B, A, 0, 2);
  ITER(A, B, 0, 3);
  ITER(B, A, 1, 0);
  ITER(A, B, 1, 1);
  ITER(B, A, 1, 2);
  ITER(A, B, 1, 3);
  ITER(B, A, 2, 0);
  ITER(A, B, 2, 1);
  ITER(B, A, 2, 2);
  ITER(A, B, 2, 3);
  ITER(B, A, 3, 0);
  ITER(A, B, 3, 1);
  ITER(B, A, 3, 2);
  ITER(A, B, 3, 3);
  ITER(B, A, 4, 0);
  ITER(A, B, 4, 1);
  ITER(B, A, 4, 2);
  ITER(A, B, 4, 3);
  BURST(B);                                   // last iteration, no prefetch

  // ---- epilogue: C/D layout col=lane&31, row=(rg&3)+8*(rg>>2)+4*(lane>>5)
  float* ob = out + ((size_t)(n * 64 + oh * 32) * 128 + y0) * 128
              + px0 + l31;
#pragma unroll
  for (int rg = 0; rg < 16; ++rg) {
    int orow = (rg & 3) + 8 * (rg >> 2) + 4 * lhi;
    float* obr = ob + (size_t)orow * 16384;
    obr[0]   = a0[rg];
    obr[128] = a1[rg];
    obr[256] = a2[rg];
    obr[384] = a3[rg];
  }
}

extern "C" void kernel_launch(void* const* d_in, const int* in_sizes, int n_in,
                              void* d_out, int out_size, void* d_ws, size_t ws_size,
                              hipStream_t stream) {
  const float* x     = (const float*)d_in[0];   // (32,64,128,128) fp32
  const float* wgt   = (const float*)d_in[1];   // (64,64,5,5) fp32
  const float* alpha = (const float*)d_in[2];   // (1,) fp32
  float* out = (float*)d_out;

  u16* apack = (u16*)d_ws;                      // 204800 B

  k_prep<<<16,   256, 0, stream>>>(wgt, alpha, apack);
  k_conv<<<4096, 128, 0, stream>>>(x, (const u32x4*)apack, out);
}